// Round 3
// baseline (1900.987 us; speedup 1.0000x reference)
//
#include <hip/hip_runtime.h>
#include <hip/hip_bf16.h>
#include <stdint.h>

#define NTOK 49
#define CDIM 192
#define NHEADS 6

typedef __attribute__((ext_vector_type(8))) short bf16x8;
typedef __attribute__((ext_vector_type(4))) float f32x4;

// RNE float -> bf16 (bit trick)
__device__ __forceinline__ short f2b(float f) {
    uint32_t u = __float_as_uint(f);
    uint32_t r = (u + 0x7fffu + ((u >> 16) & 1u)) >> 16;
    return (short)r;
}

// Fast pack: 8 consecutive fp32 -> bf16x8
__device__ __forceinline__ bf16x8 cvt8(const float* p) {
    f32x4 a = *(const f32x4*)p;
    f32x4 b = *(const f32x4*)(p + 4);
    union { uint32_t u[4]; bf16x8 v; } r;
    uint32_t e0 = __float_as_uint(a[0]) + 0x8000u, e1 = __float_as_uint(a[1]) + 0x8000u;
    uint32_t e2 = __float_as_uint(a[2]) + 0x8000u, e3 = __float_as_uint(a[3]) + 0x8000u;
    uint32_t e4 = __float_as_uint(b[0]) + 0x8000u, e5 = __float_as_uint(b[1]) + 0x8000u;
    uint32_t e6 = __float_as_uint(b[2]) + 0x8000u, e7 = __float_as_uint(b[3]) + 0x8000u;
    r.u[0] = __builtin_amdgcn_perm(e1, e0, 0x07060302u);
    r.u[1] = __builtin_amdgcn_perm(e3, e2, 0x07060302u);
    r.u[2] = __builtin_amdgcn_perm(e5, e4, 0x07060302u);
    r.u[3] = __builtin_amdgcn_perm(e7, e6, 0x07060302u);
    return r.v;
}

// One-shot: transpose+cast qkv_w [192][576]f32 -> wt [576][192]bf16,
//           proj_w [192][192]f32 -> pwt [192][192]bf16
__global__ void transpose_w(const float* __restrict__ qkv_w,
                            const float* __restrict__ proj_w,
                            short* __restrict__ wt, short* __restrict__ pwt) {
    int idx = blockIdx.x * 256 + threadIdx.x;
    if (idx < CDIM * 3 * CDIM) {
        int c = idx / (3 * CDIM), j = idx % (3 * CDIM);
        wt[j * CDIM + c] = f2b(qkv_w[idx]);
    }
    if (idx < CDIM * CDIM) {
        int c = idx / CDIM, j = idx % CDIM;
        pwt[j * CDIM + c] = f2b(proj_w[idx]);
    }
}

// ===================== stage 1: QKV GEMM, barrier-free =====================
// One block per window, 4 waves; wave wv owns token mtile wv (16 rows).
// Double-buffered weight frags; writes head-planar padded QKV:
//   wsq/wsk: [b][h][64][32] bf16 (row = 64B), wsv: [b][h][32][64] bf16 (row = 128B).
// Pad tokens (49..63) hold bias values (finite) -> safe for stage 2.
__global__ __launch_bounds__(256, 4)
void qkv_kernel(const float* __restrict__ x, const short* __restrict__ wt,
                const float* __restrict__ qkvb,
                short* __restrict__ wsq, short* __restrict__ wsk,
                short* __restrict__ wsv) {
    const int b = blockIdx.x;
    const int tid = threadIdx.x;
    const int wv = tid >> 6;
    const int lane = tid & 63;
    const int q4 = lane >> 4;
    const int l16 = lane & 15;

    // x A-frags for own mtile (24 VGPRs)
    const float* xg = x + (size_t)b * NTOK * CDIM;
    bf16x8 zero = {};
    const int n = wv * 16 + l16;
    const bool valid = (n < NTOK);
    const float* xr = xg + n * CDIM;
    bf16x8 afr[6];
#pragma unroll
    for (int ks = 0; ks < 6; ks++)
        afr[ks] = valid ? cvt8(xr + ks * 32 + q4 * 8) : zero;

    // double-buffered weight B-frags
    bf16x8 bfr[2][6];
    {
        const short* wrow = wt + (size_t)l16 * CDIM;
#pragma unroll
        for (int ks = 0; ks < 6; ks++)
            bfr[0][ks] = *(const bf16x8*)(wrow + ks * 32 + q4 * 8);
    }

    for (int jt = 0; jt < 36; jt++) {
        int cur = jt & 1;
        if (jt + 1 < 36) {
            const short* wrow = wt + (size_t)((jt + 1) * 16 + l16) * CDIM;
#pragma unroll
            for (int ks = 0; ks < 6; ks++)
                bfr[cur ^ 1][ks] = *(const bf16x8*)(wrow + ks * 32 + q4 * 8);
        }
        f32x4 acc = (f32x4){0.f, 0.f, 0.f, 0.f};
#pragma unroll
        for (int ks = 0; ks < 6; ks++)
            acc = __builtin_amdgcn_mfma_f32_16x16x32_bf16(afr[ks], bfr[cur][ks], acc, 0, 0, 0);
        float bias = qkvb[jt * 16 + l16];
        int sect = jt / 12;                 // 0=q 1=k 2=v
        int hh = (jt % 12) >> 1;            // head
        int dbase = (jt & 1) * 16;          // dim half within head
        size_t hb = (size_t)b * NHEADS + hh;
#pragma unroll
        for (int r = 0; r < 4; r++) {
            int tok = wv * 16 + q4 * 4 + r;
            short v = f2b(acc[r] + bias);
            if (sect == 0)      wsq[(hb * 64 + tok) * 32 + dbase + l16] = v;
            else if (sect == 1) wsk[(hb * 64 + tok) * 32 + dbase + l16] = v;
            else                wsv[(hb * 32 + dbase + l16) * 64 + tok] = v;
        }
    }
}

// ===================== stage 2: attention + proj, barrier-free =====================
// One block per window, 4 fully independent waves; wave wv owns tokens wv*16..+15.
// Q/K/Vt frags loaded directly from head-planar workspace (coalesced 1KB loads).
// Per-wave LDS only for P / O layout round-trips (9 KB total).
__global__ __launch_bounds__(256, 4)
void attn_proj_kernel(const short* __restrict__ wsq, const short* __restrict__ wsk,
                      const short* __restrict__ wsv, const float* __restrict__ mask,
                      const short* __restrict__ pwt, const float* __restrict__ projb,
                      float* __restrict__ out) {
    // stride 72 sh = 36 dw ≡ 4 mod 32 -> 2-way aliasing on b128 reads (free)
    __shared__ __align__(16) short Pbuf[4][16][72];

    const int b = blockIdx.x;
    const int tid = threadIdx.x;
    const int wv = tid >> 6;
    const int lane = tid & 63;
    const int q4 = lane >> 4;
    const int l16 = lane & 15;

    // premask: mask (+ -inf for pad rows/cols); rows = wv*16 + q4*4 + r
    const float* mg = mask + (size_t)(b & 63) * NTOK * NTOK;
    float premask[4][4];
#pragma unroll
    for (int ct = 0; ct < 4; ct++)
#pragma unroll
        for (int r = 0; r < 4; r++) {
            int row = wv * 16 + q4 * 4 + r;
            int col = ct * 16 + l16;
            float mv = mg[min(row, 48) * NTOK + min(col, 48)];
            premask[ct][r] = (row < NTOK && col < NTOK) ? mv : -1e30f;
        }

    const float SCALE = 0.17677669529663687f;
    bf16x8 oa[6];   // per-head O A-frags (persistent, 24 VGPRs)

#pragma unroll
    for (int h = 0; h < NHEADS; h++) {
        size_t hb = (size_t)b * NHEADS + h;
        // S = Q K^T : 1 Q-frag + 4 K-frags, all coalesced global loads
        bf16x8 qa = *(const bf16x8*)(wsq + (hb * 64 + wv * 16 + l16) * 32 + q4 * 8);
        f32x4 accs[4];
#pragma unroll
        for (int c = 0; c < 4; c++) accs[c] = (f32x4){0.f, 0.f, 0.f, 0.f};
#pragma unroll
        for (int ct = 0; ct < 4; ct++) {
            bf16x8 kb = *(const bf16x8*)(wsk + (hb * 64 + ct * 16 + l16) * 32 + q4 * 8);
            accs[ct] = __builtin_amdgcn_mfma_f32_16x16x32_bf16(qa, kb, accs[ct], 0, 0, 0);
        }
        // softmax across 64 cols: in-lane over 4 ct + 16-lane xor shuffle
        float s[4][4], mx[4], lsum[4];
#pragma unroll
        for (int r = 0; r < 4; r++) {
            mx[r] = -3.4e38f;
#pragma unroll
            for (int ct = 0; ct < 4; ct++) {
                s[ct][r] = accs[ct][r] * SCALE + premask[ct][r];
                mx[r] = fmaxf(mx[r], s[ct][r]);
            }
        }
#pragma unroll
        for (int w2 = 1; w2 < 16; w2 <<= 1)
#pragma unroll
            for (int r = 0; r < 4; r++) mx[r] = fmaxf(mx[r], __shfl_xor(mx[r], w2));
#pragma unroll
        for (int r = 0; r < 4; r++) lsum[r] = 0.f;
#pragma unroll
        for (int ct = 0; ct < 4; ct++)
#pragma unroll
            for (int r = 0; r < 4; r++) {
                float e = __expf(s[ct][r] - mx[r]);
                s[ct][r] = e;
                lsum[r] += e;
            }
#pragma unroll
        for (int w2 = 1; w2 < 16; w2 <<= 1)
#pragma unroll
            for (int r = 0; r < 4; r++) lsum[r] += __shfl_xor(lsum[r], w2);
        // P: C-layout -> A-layout via wave-private LDS (unnormalized)
#pragma unroll
        for (int ct = 0; ct < 4; ct++)
#pragma unroll
            for (int r = 0; r < 4; r++)
                Pbuf[wv][q4 * 4 + r][ct * 16 + l16] = f2b(s[ct][r]);
        // O = P V : Vt frags direct from global
        f32x4 accp[2];
        accp[0] = (f32x4){0.f, 0.f, 0.f, 0.f};
        accp[1] = (f32x4){0.f, 0.f, 0.f, 0.f};
#pragma unroll
        for (int ks = 0; ks < 2; ks++) {
            bf16x8 pa = *(const bf16x8*)&Pbuf[wv][l16][ks * 32 + q4 * 8];
#pragma unroll
            for (int jt2 = 0; jt2 < 2; jt2++) {
                bf16x8 vb = *(const bf16x8*)(wsv + (hb * 32 + jt2 * 16 + l16) * 64 + ks * 32 + q4 * 8);
                accp[jt2] = __builtin_amdgcn_mfma_f32_16x16x32_bf16(pa, vb, accp[jt2], 0, 0, 0);
            }
        }
        float rl[4];
#pragma unroll
        for (int r = 0; r < 4; r++) rl[r] = 1.0f / lsum[r];
        // normalize + capture O as A-frag via wave-private LDS round-trip
#pragma unroll
        for (int jt2 = 0; jt2 < 2; jt2++)
#pragma unroll
            for (int r = 0; r < 4; r++)
                Pbuf[wv][q4 * 4 + r][jt2 * 16 + l16] = f2b(accp[jt2][r] * rl[r]);
        oa[h] = *(const bf16x8*)&Pbuf[wv][l16][q4 * 8];
    }

    // proj: out[tok][192] = O[tok][192] x pwt^T + bias, K=192 = 6 heads x 32
#pragma unroll
    for (int ct = 0; ct < 12; ct++) {
        f32x4 acc = (f32x4){0.f, 0.f, 0.f, 0.f};
#pragma unroll
        for (int ks = 0; ks < 6; ks++) {
            bf16x8 pb = *(const bf16x8*)(pwt + (size_t)(ct * 16 + l16) * CDIM + ks * 32 + q4 * 8);
            acc = __builtin_amdgcn_mfma_f32_16x16x32_bf16(oa[ks], pb, acc, 0, 0, 0);
        }
        float bias = projb[ct * 16 + l16];
#pragma unroll
        for (int r = 0; r < 4; r++) {
            int tok = wv * 16 + q4 * 4 + r;
            if (tok < NTOK)
                out[((size_t)b * NTOK + tok) * CDIM + ct * 16 + l16] = acc[r] + bias;
        }
    }
}

// ===================== fallback fused path (verified baseline) =====================
__global__ __launch_bounds__(256, 1)
void winattn_kernel(const float* __restrict__ x, const float* __restrict__ mask,
                    const short* __restrict__ wt, const float* __restrict__ qkvb,
                    const short* __restrict__ pwt, const float* __restrict__ projb,
                    float* __restrict__ out) {
    __shared__ __align__(16) short qbuf[2][64][40];
    __shared__ __align__(16) short kbuf[2][64][40];
    __shared__ __align__(16) short vtbuf[2][32][72];
    __shared__ __align__(16) short Pbuf[4][16][72];
    __shared__ __align__(16) short Obuf[64][40];

    const int b = blockIdx.x;
    const int tid = threadIdx.x;
    const int wv = tid >> 6;
    const int lane = tid & 63;
    const int q4 = lane >> 4;
    const int l16 = lane & 15;

    const float* xg = x + (size_t)b * NTOK * CDIM;
    bf16x8 zero = {};
    bf16x8 afr[4][6];
#pragma unroll
    for (int mt = 0; mt < 4; mt++) {
        int n = mt * 16 + l16;
        const float* xr = xg + n * CDIM;
        bool valid = (n < NTOK);
#pragma unroll
        for (int ks = 0; ks < 6; ks++)
            afr[mt][ks] = valid ? cvt8(xr + ks * 32 + q4 * 8) : zero;
    }

    const float* mg = mask + (size_t)(b & 63) * NTOK * NTOK;
    float premask[4][4];
#pragma unroll
    for (int ct = 0; ct < 4; ct++)
#pragma unroll
        for (int r = 0; r < 4; r++) {
            int row = wv * 16 + q4 * 4 + r;
            int col = ct * 16 + l16;
            float mv = mg[min(row, 48) * NTOK + min(col, 48)];
            premask[ct][r] = (row < NTOK && col < NTOK) ? mv : -1e30f;
        }

    f32x4 acco[3][4];
#pragma unroll
    for (int a = 0; a < 3; a++)
#pragma unroll
        for (int m = 0; m < 4; m++) acco[a][m] = (f32x4){0.f, 0.f, 0.f, 0.f};

    const float SCALE = 0.17677669529663687f;

    for (int p = 0; p < 3; p++) {
        __syncthreads();
#pragma unroll
        for (int t = 0; t < 3; t++) {
            int i = wv * 3 + t;
            int jt;
            if (i < 4)      jt = 4 * p + i;
            else if (i < 8) jt = 12 + 4 * p + (i - 4);
            else            jt = 24 + 4 * p + (i - 8);
            int jb = jt * 16;
            const short* wrow = wt + (size_t)(jb + l16) * CDIM;
            bf16x8 bfr[6];
#pragma unroll
            for (int ks = 0; ks < 6; ks++)
                bfr[ks] = *(const bf16x8*)(wrow + ks * 32 + q4 * 8);
            f32x4 acc[4];
#pragma unroll
            for (int m = 0; m < 4; m++) acc[m] = (f32x4){0.f, 0.f, 0.f, 0.f};
#pragma unroll
            for (int ks = 0; ks < 6; ks++)
#pragma unroll
                for (int mt = 0; mt < 4; mt++)
                    acc[mt] = __builtin_amdgcn_mfma_f32_16x16x32_bf16(afr[mt][ks], bfr[ks], acc[mt], 0, 0, 0);
            float bias = qkvb[jb + l16];
            int sect = jb / CDIM;
            int jm = jb % CDIM;
            int hl = (jm / 32) - 2 * p;
            int d = (jm % 32) + l16;
#pragma unroll
            for (int mt = 0; mt < 4; mt++)
#pragma unroll
                for (int r = 0; r < 4; r++) {
                    int row = mt * 16 + q4 * 4 + r;
                    short v = f2b(acc[mt][r] + bias);
                    if (sect == 0)      qbuf[hl][row][d] = v;
                    else if (sect == 1) kbuf[hl][row][d] = v;
                    else                vtbuf[hl][d][row] = v;
                }
        }
        __syncthreads();

#pragma unroll
        for (int hl = 0; hl < 2; hl++) {
            int h = 2 * p + hl;
            f32x4 accs[4];
#pragma unroll
            for (int c = 0; c < 4; c++) accs[c] = (f32x4){0.f, 0.f, 0.f, 0.f};
            bf16x8 qa = *(const bf16x8*)&qbuf[hl][wv * 16 + l16][q4 * 8];
#pragma unroll
            for (int ct = 0; ct < 4; ct++) {
                bf16x8 kb = *(const bf16x8*)&kbuf[hl][ct * 16 + l16][q4 * 8];
                accs[ct] = __builtin_amdgcn_mfma_f32_16x16x32_bf16(qa, kb, accs[ct], 0, 0, 0);
            }
            float s[4][4], mx[4], lsum[4];
#pragma unroll
            for (int r = 0; r < 4; r++) {
                mx[r] = -3.4e38f;
#pragma unroll
                for (int ct = 0; ct < 4; ct++) {
                    s[ct][r] = accs[ct][r] * SCALE + premask[ct][r];
                    mx[r] = fmaxf(mx[r], s[ct][r]);
                }
            }
#pragma unroll
            for (int w2 = 1; w2 < 16; w2 <<= 1)
#pragma unroll
                for (int r = 0; r < 4; r++) mx[r] = fmaxf(mx[r], __shfl_xor(mx[r], w2));
#pragma unroll
            for (int r = 0; r < 4; r++) lsum[r] = 0.f;
#pragma unroll
            for (int ct = 0; ct < 4; ct++)
#pragma unroll
                for (int r = 0; r < 4; r++) {
                    float e = __expf(s[ct][r] - mx[r]);
                    s[ct][r] = e;
                    lsum[r] += e;
                }
#pragma unroll
            for (int w2 = 1; w2 < 16; w2 <<= 1)
#pragma unroll
                for (int r = 0; r < 4; r++) lsum[r] += __shfl_xor(lsum[r], w2);
#pragma unroll
            for (int ct = 0; ct < 4; ct++)
#pragma unroll
                for (int r = 0; r < 4; r++)
                    Pbuf[wv][q4 * 4 + r][ct * 16 + l16] = f2b(s[ct][r]);
            f32x4 accp[2];
            accp[0] = (f32x4){0.f, 0.f, 0.f, 0.f};
            accp[1] = (f32x4){0.f, 0.f, 0.f, 0.f};
#pragma unroll
            for (int ks = 0; ks < 2; ks++) {
                bf16x8 pa = *(const bf16x8*)&Pbuf[wv][l16][ks * 32 + q4 * 8];
#pragma unroll
                for (int jt = 0; jt < 2; jt++) {
                    bf16x8 vb = *(const bf16x8*)&vtbuf[hl][jt * 16 + l16][ks * 32 + q4 * 8];
                    accp[jt] = __builtin_amdgcn_mfma_f32_16x16x32_bf16(pa, vb, accp[jt], 0, 0, 0);
                }
            }
            __syncthreads();
            float rl[4];
#pragma unroll
            for (int r = 0; r < 4; r++) rl[r] = 1.0f / lsum[r];
#pragma unroll
            for (int jt = 0; jt < 2; jt++)
#pragma unroll
                for (int r = 0; r < 4; r++)
                    Obuf[wv * 16 + q4 * 4 + r][jt * 16 + l16] = f2b(accp[jt][r] * rl[r]);
            __syncthreads();
#pragma unroll
            for (int jtl = 0; jtl < 3; jtl++) {
                int jb = (wv * 3 + jtl) * 16;
                bf16x8 pb = *(const bf16x8*)(pwt + (size_t)(jb + l16) * CDIM + h * 32 + q4 * 8);
#pragma unroll
                for (int mt = 0; mt < 4; mt++) {
                    bf16x8 oa = *(const bf16x8*)&Obuf[mt * 16 + l16][q4 * 8];
                    acco[jtl][mt] = __builtin_amdgcn_mfma_f32_16x16x32_bf16(oa, pb, acco[jtl][mt], 0, 0, 0);
                }
            }
        }
    }

#pragma unroll
    for (int jtl = 0; jtl < 3; jtl++) {
        int jb = (wv * 3 + jtl) * 16;
        float bias = projb[jb + l16];
#pragma unroll
        for (int mt = 0; mt < 4; mt++)
#pragma unroll
            for (int r = 0; r < 4; r++) {
                int n = mt * 16 + q4 * 4 + r;
                if (n < NTOK)
                    out[((size_t)b * NTOK + n) * CDIM + jb + l16] = acco[jtl][mt][r] + bias;
            }
    }
}

extern "C" void kernel_launch(void* const* d_in, const int* in_sizes, int n_in,
                              void* d_out, int out_size, void* d_ws, size_t ws_size,
                              hipStream_t stream) {
    const float* x      = (const float*)d_in[0];
    const float* mask   = (const float*)d_in[1];
    const float* qkv_w  = (const float*)d_in[2];
    const float* qkv_b  = (const float*)d_in[3];
    const float* proj_w = (const float*)d_in[4];
    const float* proj_b = (const float*)d_in[5];
    short* wt  = (short*)d_ws;                 // [576][192] bf16
    short* pwt = wt + CDIM * 3 * CDIM;         // [192][192] bf16
    float* out = (float*)d_out;
    int B = in_sizes[0] / (NTOK * CDIM);       // 4096

    transpose_w<<<(CDIM * 3 * CDIM + 255) / 256, 256, 0, stream>>>(qkv_w, proj_w, wt, pwt);

    size_t wshorts = (size_t)(CDIM * 3 * CDIM + CDIM * CDIM);
    size_t plane   = (size_t)B * NHEADS * 64 * 32;            // shorts per q/k/v plane
    size_t need    = (wshorts + 3 * plane) * sizeof(short);   // ~303 MB
    if (ws_size >= need) {
        short* wsq = pwt + CDIM * CDIM;
        short* wsk = wsq + plane;
        short* wsv = wsk + plane;
        qkv_kernel<<<B, 256, 0, stream>>>(x, wt, qkv_b, wsq, wsk, wsv);
        attn_proj_kernel<<<B, 256, 0, stream>>>(wsq, wsk, wsv, mask, pwt, proj_b, out);
    } else {
        winattn_kernel<<<B, 256, 0, stream>>>(x, mask, wt, qkv_b, pwt, proj_b, out);
    }
}

// Round 4
// 519.834 us; speedup vs baseline: 3.6569x; 3.6569x over previous
//
#include <hip/hip_runtime.h>
#include <hip/hip_bf16.h>
#include <stdint.h>

#define NTOK 49
#define CDIM 192
#define NHEADS 6

typedef __attribute__((ext_vector_type(8))) short bf16x8;
typedef __attribute__((ext_vector_type(4))) float f32x4;

// RNE float -> bf16 (bit trick)
__device__ __forceinline__ short f2b(float f) {
    uint32_t u = __float_as_uint(f);
    uint32_t r = (u + 0x7fffu + ((u >> 16) & 1u)) >> 16;
    return (short)r;
}

// Fast pack: 8 consecutive fp32 -> bf16x8
__device__ __forceinline__ bf16x8 cvt8(const float* p) {
    f32x4 a = *(const f32x4*)p;
    f32x4 b = *(const f32x4*)(p + 4);
    union { uint32_t u[4]; bf16x8 v; } r;
    uint32_t e0 = __float_as_uint(a[0]) + 0x8000u, e1 = __float_as_uint(a[1]) + 0x8000u;
    uint32_t e2 = __float_as_uint(a[2]) + 0x8000u, e3 = __float_as_uint(a[3]) + 0x8000u;
    uint32_t e4 = __float_as_uint(b[0]) + 0x8000u, e5 = __float_as_uint(b[1]) + 0x8000u;
    uint32_t e6 = __float_as_uint(b[2]) + 0x8000u, e7 = __float_as_uint(b[3]) + 0x8000u;
    r.u[0] = __builtin_amdgcn_perm(e1, e0, 0x07060302u);
    r.u[1] = __builtin_amdgcn_perm(e3, e2, 0x07060302u);
    r.u[2] = __builtin_amdgcn_perm(e5, e4, 0x07060302u);
    r.u[3] = __builtin_amdgcn_perm(e7, e6, 0x07060302u);
    return r.v;
}

// One-shot: transpose+cast qkv_w [192][576]f32 -> wt [576][192]bf16,
//           proj_w [192][192]f32 -> pwt [192][192]bf16
__global__ void transpose_w(const float* __restrict__ qkv_w,
                            const float* __restrict__ proj_w,
                            short* __restrict__ wt, short* __restrict__ pwt) {
    int idx = blockIdx.x * 256 + threadIdx.x;
    if (idx < CDIM * 3 * CDIM) {
        int c = idx / (3 * CDIM), j = idx % (3 * CDIM);
        wt[j * CDIM + c] = f2b(qkv_w[idx]);
    }
    if (idx < CDIM * CDIM) {
        int c = idx / CDIM, j = idx % CDIM;
        pwt[j * CDIM + c] = f2b(proj_w[idx]);
    }
}

// Fused window-attention. One block per window, 4 waves.
// QKV phase: wave owns all 4 token-mtiles for 3 of 12 jtiles (baseline-proven).
// Attention phase: wave -> (head = wv&1, token-half = wv>>1): both heads of the
//   pair run in parallel, each wave drives 2 independent softmax chains (2x ILP).
// Proj phase: ONCE at the end over full K=192 from Obuf (6-deep MFMA ILP).
// Barriers: 2 per pair + 1 before proj = 7 (was 18).
__global__ __launch_bounds__(256, 2)
void winattn_kernel(const float* __restrict__ x, const float* __restrict__ mask,
                    const short* __restrict__ wt, const float* __restrict__ qkvb,
                    const short* __restrict__ pwt, const float* __restrict__ projb,
                    float* __restrict__ out) {
    // LDS 72.5 KB -> 2 blocks/CU.
    __shared__ __align__(16) short qbuf[2][64][40];   // 10240 B [head-in-pair][token][d]
    __shared__ __align__(16) short kbuf[2][64][40];   // 10240 B
    __shared__ __align__(16) short vtbuf[2][32][72];  //  9216 B [head-in-pair][d][token]
    __shared__ __align__(16) short Pbuf[4][32][72];   // 18432 B per-wave P rows (2 mtiles)
    __shared__ __align__(16) short Obuf[64][204];     // 26112 B O for ALL heads [token][h*32+d]
                                                      // stride 204 sh = 102 dw = 6 mod 32 -> spread banks

    const int b = blockIdx.x;
    const int tid = threadIdx.x;
    const int wv = tid >> 6;       // wave 0..3
    const int lane = tid & 63;
    const int q4 = lane >> 4;      // quad 0..3
    const int l16 = lane & 15;
    const int hl = wv & 1;         // attn: head within pair
    const int mh = wv >> 1;        // attn: token half (rows mh*32 .. mh*32+31)

    // ---- persistent x A-fragments: all 4 mtiles x 6 ksteps (96 VGPRs) ----
    const float* xg = x + (size_t)b * NTOK * CDIM;
    bf16x8 zero = {};
    bf16x8 afr[4][6];
#pragma unroll
    for (int mt = 0; mt < 4; mt++) {
        int n = mt * 16 + l16;
        const float* xr = xg + n * CDIM;
        bool valid = (n < NTOK);
#pragma unroll
        for (int ks = 0; ks < 6; ks++)
            afr[mt][ks] = valid ? cvt8(xr + ks * 32 + q4 * 8) : zero;
    }

    // ---- premask for the attn row assignment: rows = mh*32 + mi*16 + q4*4 + r ----
    const float* mg = mask + (size_t)(b & 63) * NTOK * NTOK;
    float premask[2][4][4];
#pragma unroll
    for (int mi = 0; mi < 2; mi++)
#pragma unroll
        for (int ct = 0; ct < 4; ct++)
#pragma unroll
            for (int r = 0; r < 4; r++) {
                int row = mh * 32 + mi * 16 + q4 * 4 + r;
                int col = ct * 16 + l16;
                float mv = mg[min(row, 48) * NTOK + min(col, 48)];
                premask[mi][ct][r] = (row < NTOK && col < NTOK) ? mv : -1e30f;
            }

    const float SCALE = 0.17677669529663687f;

    for (int p = 0; p < 3; p++) {            // head pairs (2p, 2p+1)
        __syncthreads();                     // q/k/vt overwrite vs prior pair's attn reads

        // ================= QKV for this head pair (baseline structure) =================
#pragma unroll
        for (int t = 0; t < 3; t++) {
            int i = wv * 3 + t;              // 12 jtiles / 4 waves
            int jt;
            if (i < 4)      jt = 4 * p + i;            // q cols
            else if (i < 8) jt = 12 + 4 * p + (i - 4); // k cols
            else            jt = 24 + 4 * p + (i - 8); // v cols
            int jb = jt * 16;
            const short* wrow = wt + (size_t)(jb + l16) * CDIM;
            bf16x8 bfr[6];
#pragma unroll
            for (int ks = 0; ks < 6; ks++)
                bfr[ks] = *(const bf16x8*)(wrow + ks * 32 + q4 * 8);
            f32x4 acc[4];
#pragma unroll
            for (int m = 0; m < 4; m++) acc[m] = (f32x4){0.f, 0.f, 0.f, 0.f};
#pragma unroll
            for (int ks = 0; ks < 6; ks++)
#pragma unroll
                for (int mt = 0; mt < 4; mt++)
                    acc[mt] = __builtin_amdgcn_mfma_f32_16x16x32_bf16(afr[mt][ks], bfr[ks], acc[mt], 0, 0, 0);
            float bias = qkvb[jb + l16];
            int sect = jb / CDIM;            // 0=q 1=k 2=v
            int jm = jb % CDIM;
            int hw = (jm / 32) - 2 * p;      // head within pair
            int d = (jm % 32) + l16;
#pragma unroll
            for (int mt = 0; mt < 4; mt++)
#pragma unroll
                for (int r = 0; r < 4; r++) {
                    int row = mt * 16 + q4 * 4 + r;
                    short v = f2b(acc[mt][r] + bias);
                    if (sect == 0)      qbuf[hw][row][d] = v;
                    else if (sect == 1) kbuf[hw][row][d] = v;
                    else                vtbuf[hw][d][row] = v;
                }
        }
        __syncthreads();                     // K/V visible to all waves

        // ================= attention: head hl, rows mh*32..mh*32+31 =================
        {
            const int h = 2 * p + hl;
            // S = Q K^T : 2 mtiles x 4 ctiles (8 independent MFMAs)
            f32x4 accs[2][4];
#pragma unroll
            for (int mi = 0; mi < 2; mi++)
#pragma unroll
                for (int c = 0; c < 4; c++) accs[mi][c] = (f32x4){0.f, 0.f, 0.f, 0.f};
            bf16x8 qa[2];
#pragma unroll
            for (int mi = 0; mi < 2; mi++)
                qa[mi] = *(const bf16x8*)&qbuf[hl][mh * 32 + mi * 16 + l16][q4 * 8];
#pragma unroll
            for (int ct = 0; ct < 4; ct++) {
                bf16x8 kb = *(const bf16x8*)&kbuf[hl][ct * 16 + l16][q4 * 8];
#pragma unroll
                for (int mi = 0; mi < 2; mi++)
                    accs[mi][ct] = __builtin_amdgcn_mfma_f32_16x16x32_bf16(qa[mi], kb, accs[mi][ct], 0, 0, 0);
            }
            // softmax: two independent chains (mi=0,1) interleave
            float s[2][4][4], mx[2][4], lsum[2][4];
#pragma unroll
            for (int mi = 0; mi < 2; mi++)
#pragma unroll
                for (int r = 0; r < 4; r++) {
                    mx[mi][r] = -3.4e38f;
#pragma unroll
                    for (int ct = 0; ct < 4; ct++) {
                        s[mi][ct][r] = accs[mi][ct][r] * SCALE + premask[mi][ct][r];
                        mx[mi][r] = fmaxf(mx[mi][r], s[mi][ct][r]);
                    }
                }
#pragma unroll
            for (int w2 = 1; w2 < 16; w2 <<= 1)
#pragma unroll
                for (int mi = 0; mi < 2; mi++)
#pragma unroll
                    for (int r = 0; r < 4; r++) mx[mi][r] = fmaxf(mx[mi][r], __shfl_xor(mx[mi][r], w2));
#pragma unroll
            for (int mi = 0; mi < 2; mi++)
#pragma unroll
                for (int r = 0; r < 4; r++) lsum[mi][r] = 0.f;
#pragma unroll
            for (int mi = 0; mi < 2; mi++)
#pragma unroll
                for (int ct = 0; ct < 4; ct++)
#pragma unroll
                    for (int r = 0; r < 4; r++) {
                        float e = __expf(s[mi][ct][r] - mx[mi][r]);
                        s[mi][ct][r] = e;
                        lsum[mi][r] += e;
                    }
#pragma unroll
            for (int w2 = 1; w2 < 16; w2 <<= 1)
#pragma unroll
                for (int mi = 0; mi < 2; mi++)
#pragma unroll
                    for (int r = 0; r < 4; r++) lsum[mi][r] += __shfl_xor(lsum[mi][r], w2);
            // P -> wave-private LDS (C-layout -> A-layout), unnormalized
#pragma unroll
            for (int mi = 0; mi < 2; mi++)
#pragma unroll
                for (int ct = 0; ct < 4; ct++)
#pragma unroll
                    for (int r = 0; r < 4; r++)
                        Pbuf[wv][mi * 16 + q4 * 4 + r][ct * 16 + l16] = f2b(s[mi][ct][r]);
            // O = P V : 2 mtiles x 2 jtiles x 2 ksteps
            f32x4 accp[2][2];
#pragma unroll
            for (int mi = 0; mi < 2; mi++)
#pragma unroll
                for (int j = 0; j < 2; j++) accp[mi][j] = (f32x4){0.f, 0.f, 0.f, 0.f};
#pragma unroll
            for (int ks = 0; ks < 2; ks++) {
                bf16x8 pa[2];
#pragma unroll
                for (int mi = 0; mi < 2; mi++)
                    pa[mi] = *(const bf16x8*)&Pbuf[wv][mi * 16 + l16][ks * 32 + q4 * 8];
#pragma unroll
                for (int jt2 = 0; jt2 < 2; jt2++) {
                    bf16x8 vb = *(const bf16x8*)&vtbuf[hl][jt2 * 16 + l16][ks * 32 + q4 * 8];
#pragma unroll
                    for (int mi = 0; mi < 2; mi++)
                        accp[mi][jt2] = __builtin_amdgcn_mfma_f32_16x16x32_bf16(pa[mi], vb, accp[mi][jt2], 0, 0, 0);
                }
            }
            // normalize + write O columns for this head (disjoint rows+cols across waves)
#pragma unroll
            for (int mi = 0; mi < 2; mi++) {
                float rl[4];
#pragma unroll
                for (int r = 0; r < 4; r++) rl[r] = 1.0f / lsum[mi][r];
#pragma unroll
                for (int jt2 = 0; jt2 < 2; jt2++)
#pragma unroll
                    for (int r = 0; r < 4; r++)
                        Obuf[mh * 32 + mi * 16 + q4 * 4 + r][h * 32 + jt2 * 16 + l16] =
                            f2b(accp[mi][jt2][r] * rl[r]);
            }
        }
    }

    __syncthreads();   // Obuf complete for all 6 heads

    // ================= proj: out = O[64][192] x pwt^T + bias, K=192 =================
    // pwt B-frags hoisted (18 frags = 72 VGPRs; afr dead by now)
    bf16x8 pb[3][6];
#pragma unroll
    for (int jtl = 0; jtl < 3; jtl++) {
        int jb = (wv * 3 + jtl) * 16;
        const short* wrow = pwt + (size_t)(jb + l16) * CDIM;
#pragma unroll
        for (int ks = 0; ks < 6; ks++)
            pb[jtl][ks] = *(const bf16x8*)(wrow + ks * 32 + q4 * 8);
    }
#pragma unroll
    for (int mt = 0; mt < 4; mt++) {
        bf16x8 oafr[6];
#pragma unroll
        for (int ks = 0; ks < 6; ks++)
            oafr[ks] = *(const bf16x8*)&Obuf[mt * 16 + l16][ks * 32 + q4 * 8];
#pragma unroll
        for (int jtl = 0; jtl < 3; jtl++) {
            int jb = (wv * 3 + jtl) * 16;
            f32x4 acc = (f32x4){0.f, 0.f, 0.f, 0.f};
#pragma unroll
            for (int ks = 0; ks < 6; ks++)
                acc = __builtin_amdgcn_mfma_f32_16x16x32_bf16(oafr[ks], pb[jtl][ks], acc, 0, 0, 0);
            float bias = projb[jb + l16];
#pragma unroll
            for (int r = 0; r < 4; r++) {
                int n = mt * 16 + q4 * 4 + r;
                if (n < NTOK)
                    out[((size_t)b * NTOK + n) * CDIM + jb + l16] = acc[r] + bias;
            }
        }
    }
}

extern "C" void kernel_launch(void* const* d_in, const int* in_sizes, int n_in,
                              void* d_out, int out_size, void* d_ws, size_t ws_size,
                              hipStream_t stream) {
    const float* x      = (const float*)d_in[0];
    const float* mask   = (const float*)d_in[1];
    const float* qkv_w  = (const float*)d_in[2];
    const float* qkv_b  = (const float*)d_in[3];
    const float* proj_w = (const float*)d_in[4];
    const float* proj_b = (const float*)d_in[5];
    short* wt  = (short*)d_ws;                 // [576][192] bf16
    short* pwt = wt + CDIM * 3 * CDIM;         // [192][192] bf16
    float* out = (float*)d_out;
    int B = in_sizes[0] / (NTOK * CDIM);       // 4096

    transpose_w<<<(CDIM * 3 * CDIM + 255) / 256, 256, 0, stream>>>(qkv_w, proj_w, wt, pwt);
    winattn_kernel<<<B, 256, 0, stream>>>(x, mask, wt, qkv_b, pwt, proj_b, out);
}